// Round 10
// baseline (84.468 us; speedup 1.0000x reference)
//
#include <hip/hip_runtime.h>
#include <hip/hip_bf16.h>
#include <math.h>

#define B_ 2
#define T_ 2048
#define D_ 512
#define H_ 16
#define DH 32
#define L_ 64
#define C_ 32
#define NC 1024    // total chunks
#define VTP 72     // LDS row stride (ushorts) for chunk kernels
#define CSZ 1056   // valid floats per chunk state tile (33 rows x 32)
#define PST 36     // LDS prefix row stride (floats): 144B, 16B-aligned, bank-spread

typedef __attribute__((ext_vector_type(8))) short bf16x8;
typedef __attribute__((ext_vector_type(4))) float f32x4;
typedef __attribute__((ext_vector_type(4))) unsigned short u16x4;

#define AS1 __attribute__((address_space(1)))
#define AS3 __attribute__((address_space(3)))

__device__ __forceinline__ float bf2f(unsigned short u) {
    union { float f; unsigned int i; } v; v.i = ((unsigned int)u) << 16; return v.f;
}
__device__ __forceinline__ unsigned short f2bf(float f) {
    union { float f; unsigned int u; } v; v.f = f;
    unsigned int u = v.u;
    unsigned int r = u + 0x7FFFu + ((u >> 16) & 1u);
    return (unsigned short)(r >> 16);
}
// compiler-visible RNE conversion (lets hipcc emit v_cvt_pk_bf16_f32 for pairs)
__device__ __forceinline__ unsigned short f2bf_rne(float f) {
    __hip_bfloat16 h = __float2bfloat16(f);
    union { __hip_bfloat16 h; unsigned short u; } v; v.h = h; return v.u;
}
__device__ __forceinline__ bf16x8 phi_frag(bf16x8 in) {
    bf16x8 r;
    #pragma unroll
    for (int i = 0; i < 8; ++i) {
        float f = bf2f((unsigned short)in[i]);
        f = f > 0.f ? f + 1.f : __expf(f);
        r[i] = (short)f2bf(f);
    }
    return r;
}
__device__ __forceinline__ void gload_lds16(const unsigned short* g, unsigned short* l) {
    __builtin_amdgcn_global_load_lds((const AS1 unsigned int*)g, (AS3 unsigned int*)l, 16, 0, 0);
}

// C[m][n] = sum_k A[m][k]*W[n][k]; BMx128 tile, 4 waves (2x2), 16x16x32 bf16 MFMA.
// W is always fp32, converted during reg-staging (T14: load early, cvt+ds_write late).
// A is fp32 (reg-staged convert) when AF32, else bf16 via async global_load_lds.
template<int BM, bool AF32, bool OUT_BF16>
__global__ __launch_bounds__(256) void gemm_nt(const void* __restrict__ Aptr,
                                               const float* __restrict__ Wf,
                                               void* __restrict__ Cout,
                                               int N, int K)
{
    constexpr int MF = BM / 32;        // m-fragments per wave
    constexpr int AF4 = BM / 32;       // float4 loads per lane for fp32 A staging
    __shared__ unsigned short As[2][BM][32];
    __shared__ unsigned short Bs[2][128][32];
    const int tid = threadIdx.x;
    const int lane = tid & 63;
    const int wave = tid >> 6;
    const int wr = wave >> 1;
    const int wc = wave & 1;
    const size_t bm = (size_t)blockIdx.x * BM;
    const size_t bn = (size_t)blockIdx.y * 128;

    const int r8 = lane >> 3;          // 0..7 (f32 staging row-in-group)
    const int c4 = (lane & 7) * 4;     // f32 staging col (floats)
    const int lrow = lane >> 2;        // bf16 gload row
    const int lcol = (lane & 3) * 8;   // bf16 gload col

    const float* agf = nullptr;
    const unsigned short* agb = nullptr;
    if constexpr (AF32) agf = (const float*)Aptr + (bm + wave * (BM / 4) + r8) * (size_t)K + c4;
    else                agb = (const unsigned short*)Aptr + (bm + wave * (BM / 4) + lrow) * (size_t)K + lcol;
    const float* wgf = Wf + (bn + wave * 32 + r8) * (size_t)K + c4;

    f32x4 aL[AF4];
    f32x4 wL[4];

    auto load_stage = [&](int buf, int k0) {
        if constexpr (AF32) {
            #pragma unroll
            for (int i = 0; i < AF4; ++i)
                aL[i] = *(const f32x4*)(agf + k0 + (size_t)(i * 8) * K);
        } else {
            gload_lds16(agb + k0, &As[buf][wave * (BM / 4)][0]);
            if constexpr (BM / 4 == 32)
                gload_lds16(agb + (size_t)16 * K + k0, &As[buf][wave * (BM / 4) + 16][0]);
        }
        #pragma unroll
        for (int i = 0; i < 4; ++i)
            wL[i] = *(const f32x4*)(wgf + k0 + (size_t)(i * 8) * K);
    };
    auto write_stage = [&](int buf) {
        if constexpr (AF32) {
            #pragma unroll
            for (int i = 0; i < AF4; ++i) {
                u16x4 o;
                o.x = f2bf_rne(aL[i][0]); o.y = f2bf_rne(aL[i][1]);
                o.z = f2bf_rne(aL[i][2]); o.w = f2bf_rne(aL[i][3]);
                *(u16x4*)&As[buf][wave * (BM / 4) + r8 + i * 8][c4] = o;
            }
        }
        #pragma unroll
        for (int i = 0; i < 4; ++i) {
            u16x4 o;
            o.x = f2bf_rne(wL[i][0]); o.y = f2bf_rne(wL[i][1]);
            o.z = f2bf_rne(wL[i][2]); o.w = f2bf_rne(wL[i][3]);
            *(u16x4*)&Bs[buf][wave * 32 + r8 + i * 8][c4] = o;
        }
    };

    f32x4 acc[MF][4];
    #pragma unroll
    for (int m = 0; m < MF; ++m)
        #pragma unroll
        for (int n = 0; n < 4; ++n)
            acc[m][n] = (f32x4){0.f, 0.f, 0.f, 0.f};

    const int rr = lane & 15;
    const int kb = (lane >> 4) * 8;

    load_stage(0, 0);
    write_stage(0);
    __syncthreads();
    int cur = 0;
    for (int k0 = 0; k0 < K; k0 += 32) {
        const bool more = k0 + 32 < K;
        if (more) load_stage(cur ^ 1, k0 + 32);   // issue loads early (latency under MFMA)
        bf16x8 af[MF], bfr[4];
        #pragma unroll
        for (int m = 0; m < MF; ++m)
            af[m] = *(const bf16x8*)&As[cur][wr * (BM / 2) + m * 16 + rr][kb];
        #pragma unroll
        for (int n = 0; n < 4; ++n)
            bfr[n] = *(const bf16x8*)&Bs[cur][wc * 64 + n * 16 + rr][kb];
        #pragma unroll
        for (int m = 0; m < MF; ++m)
            #pragma unroll
            for (int n = 0; n < 4; ++n)
                acc[m][n] = __builtin_amdgcn_mfma_f32_16x16x32_bf16(af[m], bfr[n], acc[m][n], 0, 0, 0);
        if (more) write_stage(cur ^ 1);           // convert + ds_write late
        __syncthreads();
        cur ^= 1;
    }

    const int cr = (lane >> 4) * 4;
    const int cc = lane & 15;
    #pragma unroll
    for (int m = 0; m < MF; ++m)
        #pragma unroll
        for (int n = 0; n < 4; ++n)
            #pragma unroll
            for (int j = 0; j < 4; ++j) {
                size_t row = bm + wr * (BM / 2) + m * 16 + cr + j;
                size_t col = bn + wc * 64 + n * 16 + cc;
                float v = acc[m][n][j];
                if (OUT_BF16) ((unsigned short*)Cout)[row * N + col] = f2bf(v);
                else          ((float*)Cout)[row * N + col] = v;
            }
}

// Per-chunk ST[e][d] = sum_t v_ext[t][e]*phi(k)[t][d], e=0..32 (row 32 = ksum).
// Output tile: CSZ=1056 floats per chunk (rows 0..32 x 32 cols).
__global__ __launch_bounds__(256) void chunk_sum(const unsigned short* __restrict__ qkv,
                                                 float* __restrict__ cSf)
{
    __shared__ unsigned short Kt[4][DH][VTP];
    __shared__ unsigned short Vt[4][48][VTP];
    const int tid = threadIdx.x;
    const int lane = tid & 63;
    const int wave = tid >> 6;
    const int chunk = blockIdx.x * 4 + wave;
    const int c = chunk & 31;
    const int h = (chunk >> 5) & 15;
    const int b = chunk >> 9;
    const size_t rowbase = ((size_t)(b * T_ + c * L_)) * (3 * D_) + h * DH;
    const int half = lane & 1;

    #pragma unroll
    for (int it = 0; it < 2; ++it) {
        int t = (lane >> 1) + it * 32;
        const unsigned short* kp = qkv + rowbase + (size_t)t * (3 * D_) + D_ + half * 16;
        const unsigned short* vp = qkv + rowbase + (size_t)t * (3 * D_) + 2 * D_ + half * 16;
        bf16x8 k0 = phi_frag(*(const bf16x8*)kp);
        bf16x8 k1 = phi_frag(*(const bf16x8*)(kp + 8));
        bf16x8 v0 = *(const bf16x8*)vp;
        bf16x8 v1 = *(const bf16x8*)(vp + 8);
        #pragma unroll
        for (int i = 0; i < 8; ++i) {
            Kt[wave][half * 16 + i][t]     = (unsigned short)k0[i];
            Kt[wave][half * 16 + 8 + i][t] = (unsigned short)k1[i];
            Vt[wave][half * 16 + i][t]     = (unsigned short)v0[i];
            Vt[wave][half * 16 + 8 + i][t] = (unsigned short)v1[i];
        }
    }
    Vt[wave][32][lane] = 0x3F80;   // ones row

    const int fr = lane & 15;
    const int fg = lane >> 4;
    f32x4 acc[3][2];
    #pragma unroll
    for (int m = 0; m < 3; ++m)
        #pragma unroll
        for (int n = 0; n < 2; ++n)
            acc[m][n] = (f32x4){0.f, 0.f, 0.f, 0.f};

    #pragma unroll
    for (int ks = 0; ks < 2; ++ks) {
        int toff = fg * 8 + ks * 32;
        bf16x8 av[3], bk[2];
        #pragma unroll
        for (int m = 0; m < 3; ++m) av[m] = *(const bf16x8*)&Vt[wave][m * 16 + fr][toff];
        #pragma unroll
        for (int n = 0; n < 2; ++n) bk[n] = *(const bf16x8*)&Kt[wave][n * 16 + fr][toff];
        #pragma unroll
        for (int m = 0; m < 3; ++m)
            #pragma unroll
            for (int n = 0; n < 2; ++n)
                acc[m][n] = __builtin_amdgcn_mfma_f32_16x16x32_bf16(av[m], bk[n], acc[m][n], 0, 0, 0);
    }

    float* outp = cSf + (size_t)chunk * CSZ;
    #pragma unroll
    for (int m = 0; m < 2; ++m)
        #pragma unroll
        for (int n = 0; n < 2; ++n)
            #pragma unroll
            for (int r = 0; r < 4; ++r)
                outp[(m * 16 + fg * 4 + r) * 32 + n * 16 + fr] = acc[m][n][r];
    if (fg == 0) {
        #pragma unroll
        for (int n = 0; n < 2; ++n)
            outp[32 * 32 + n * 16 + fr] = acc[2][n][0];
    }
}

// Per-chunk output via MFMA, with the exclusive chunk-prefix computed
// block-cooperatively (coalesced streaming of preceding cSf tiles into LDS).
// 2 waves per chunk (row halves), 2 consecutive chunks (same bh) per block.
__global__ __launch_bounds__(256) void chunk_out(const unsigned short* __restrict__ qkv,
                                                 const float* __restrict__ cSf,
                                                 unsigned short* __restrict__ attn)
{
    __shared__ unsigned short Vt[2][48][VTP];
    __shared__ unsigned short Am[4][32][VTP];
    __shared__ float P[2][48 * PST];
    const int tid = threadIdx.x;
    const int lane = tid & 63;
    const int wave = tid >> 6;
    const int ci = wave >> 1;
    const int wh = wave & 1;
    const int chunk = blockIdx.x * 2 + ci;
    const int c = chunk & 31;
    const int h = (chunk >> 5) & 15;
    const int b = chunk >> 9;
    const size_t rowbase = ((size_t)(b * T_ + c * L_)) * (3 * D_) + h * DH;
    const int fr = lane & 15;
    const int fg = lane >> 4;

    // V staging (independent of P; issue first so HBM latency overlaps prefix loop)
    {
        int t = wh * 32 + (lane >> 1);
        int half = lane & 1;
        const unsigned short* vp = qkv + rowbase + (size_t)t * (3 * D_) + 2 * D_ + half * 16;
        bf16x8 v0 = *(const bf16x8*)vp;
        bf16x8 v1 = *(const bf16x8*)(vp + 8);
        #pragma unroll
        for (int i = 0; i < 8; ++i) {
            Vt[ci][half * 16 + i][t]     = (unsigned short)v0[i];
            Vt[ci][half * 16 + 8 + i][t] = (unsigned short)v1[i];
        }
        if (half == 0) Vt[ci][32][t] = 0x3F80;
    }
    bf16x8 aq[2];
    #pragma unroll
    for (int mm = 0; mm < 2; ++mm) {
        int m = wh * 2 + mm;
        const unsigned short* qp = qkv + rowbase + (size_t)(m * 16 + fr) * (3 * D_) + fg * 8;
        aq[mm] = phi_frag(*(const bf16x8*)qp);
    }
    bf16x8 bk[4];
    const int nmax = wh * 2 + 1;
    #pragma unroll
    for (int n = 0; n < 4; ++n) {
        if (n <= nmax) {
            const unsigned short* kp = qkv + rowbase + (size_t)(n * 16 + fr) * (3 * D_) + D_ + fg * 8;
            bk[n] = phi_frag(*(const bf16x8*)kp);
        }
    }

    // ---- cooperative exclusive prefix into P[0] (chunk c1) and P[1] (chunk c1+1)
    // zero rows 33..47 (feed unused accumulator columns; must be finite)
    for (int idx = tid; idx < 2 * 15 * PST; idx += 256) {
        int pi = idx / (15 * PST);
        P[pi][33 * PST + idx % (15 * PST)] = 0.f;
    }
    {
        const int c1 = (blockIdx.x * 2) & 31;
        const int cbase = blockIdx.x * 2 - c1;     // global chunk id of c=0 in this bh
        float s[5] = {0.f, 0.f, 0.f, 0.f, 0.f};
        #pragma unroll 4
        for (int j = 0; j < c1; ++j) {
            const float* sp = cSf + (size_t)(cbase + j) * CSZ;
            #pragma unroll
            for (int u = 0; u < 5; ++u) {
                int e = tid + u * 256;
                if (e < CSZ) s[u] += sp[e];
            }
        }
        const float* sc = cSf + (size_t)(blockIdx.x * 2) * CSZ;
        #pragma unroll
        for (int u = 0; u < 5; ++u) {
            int e = tid + u * 256;
            if (e < CSZ) {
                int r_ = e >> 5, c_ = e & 31;
                P[0][r_ * PST + c_] = s[u];
                P[1][r_ * PST + c_] = s[u] + sc[e];
            }
        }
    }
    __syncthreads();

    // B-fragments of the prefix state from LDS (f32 -> bf16 RNE, same as old cSt path)
    bf16x8 bkv[3];
    #pragma unroll
    for (int n = 0; n < 3; ++n) {
        f32x4 lo = *(const f32x4*)&P[ci][(n * 16 + fr) * PST + fg * 8];
        f32x4 hi = *(const f32x4*)&P[ci][(n * 16 + fr) * PST + fg * 8 + 4];
        #pragma unroll
        for (int i = 0; i < 4; ++i) {
            bkv[n][i]     = (short)f2bf(lo[i]);
            bkv[n][4 + i] = (short)f2bf(hi[i]);
        }
    }

    f32x4 zero = (f32x4){0.f, 0.f, 0.f, 0.f};
    f32x4 acc[2][3];
    #pragma unroll
    for (int mm = 0; mm < 2; ++mm)
        #pragma unroll
        for (int n = 0; n < 3; ++n)
            acc[mm][n] = __builtin_amdgcn_mfma_f32_16x16x32_bf16(aq[mm], bkv[n], zero, 0, 0, 0);

    #pragma unroll
    for (int mm = 0; mm < 2; ++mm) {
        int m = wh * 2 + mm;
        #pragma unroll
        for (int n = 0; n < 4; ++n) {
            if (n <= m) {
                f32x4 s = __builtin_amdgcn_mfma_f32_16x16x32_bf16(aq[mm], bk[n], zero, 0, 0, 0);
                #pragma unroll
                for (int r = 0; r < 4; ++r) {
                    unsigned short v = f2bf(s[r]);
                    if (n == m && fr > fg * 4 + r) v = 0;
                    Am[wave][mm * 16 + fg * 4 + r][n * 16 + fr] = v;
                }
            }
        }
    }
    {
        int zc = wh ? 48 : 16;
        *(uint2*)&Am[wave][fr][zc + fg * 4] = (uint2){0u, 0u};
    }
    __syncthreads();

    #pragma unroll
    for (int ks = 0; ks < 2; ++ks) {
        if (ks <= wh) {
            bf16x8 bv[3];
            #pragma unroll
            for (int n = 0; n < 3; ++n)
                bv[n] = *(const bf16x8*)&Vt[ci][n * 16 + fr][fg * 8 + ks * 32];
            #pragma unroll
            for (int mm = 0; mm < 2; ++mm) {
                bf16x8 aa = *(const bf16x8*)&Am[wave][mm * 16 + fr][fg * 8 + ks * 32];
                #pragma unroll
                for (int n = 0; n < 3; ++n)
                    acc[mm][n] = __builtin_amdgcn_mfma_f32_16x16x32_bf16(aa, bv[n], acc[mm][n], 0, 0, 0);
            }
        }
    }

    #pragma unroll
    for (int mm = 0; mm < 2; ++mm) {
        float dn[4];
        #pragma unroll
        for (int r = 0; r < 4; ++r)
            dn[r] = __shfl(acc[mm][2][r], lane & 48);
        #pragma unroll
        for (int r = 0; r < 4; ++r) {
            float inv = 1.0f / fmaxf(dn[r], 1e-6f);
            #pragma unroll
            for (int n = 0; n < 2; ++n)
                Am[wave][mm * 16 + fg * 4 + r][n * 16 + fr] = f2bf(acc[mm][n][r] * inv);
        }
    }
    {
        int lrow = lane >> 1;
        int half = lane & 1;
        uint4 q0 = *(const uint4*)&Am[wave][lrow][half * 16];
        uint4 q1 = *(const uint4*)&Am[wave][lrow][half * 16 + 8];
        size_t grow = (size_t)(b * T_ + c * L_ + wh * 32 + lrow);
        unsigned short* dst = attn + grow * D_ + h * DH + half * 16;
        *(uint4*)dst = q0;
        *(uint4*)(dst + 8) = q1;
    }
}

extern "C" void kernel_launch(void* const* d_in, const int* in_sizes, int n_in,
                              void* d_out, int out_size, void* d_ws, size_t ws_size,
                              hipStream_t stream) {
    const float* x     = (const float*)d_in[0];
    const float* w_qkv = (const float*)d_in[1];
    const float* w_out = (const float*)d_in[2];
    float* out = (float*)d_out;

    char* ws = (char*)d_ws;
    unsigned short* qkvb  = (unsigned short*)ws;                 // 12,582,912 B
    unsigned short* attnb = (unsigned short*)(ws + 12582912);    //  4,194,304 B
    float* cSf            = (float*)(ws + 16777216);             //  4,325,376 B  [1024][1056] f32
    // total 21,102,592 B

    // 1) QKV projection: fp32 x / fp32 w_qkv -> bf16 qkv (convert fused into staging)
    gemm_nt<128, true, true><<<dim3(4096 / 128, 1536 / 128), 256, 0, stream>>>(
        x, w_qkv, qkvb, 1536, 512);

    // 2) per-chunk local sums
    chunk_sum<<<NC / 4, 256, 0, stream>>>(qkvb, cSf);

    // 3) per-chunk outputs (cooperative prefix folded in) -> bf16 attn
    chunk_out<<<NC / 2, 256, 0, stream>>>(qkvb, cSf, attnb);

    // 4) output projection: bf16 attn (gload_lds) / fp32 w_out -> fp32 out
    gemm_nt<64, false, false><<<dim3(4096 / 64, 512 / 128), 256, 0, stream>>>(
        attnb, w_out, out, 512, 512);
}

// Round 11
// 48.603 us; speedup vs baseline: 1.7379x; 1.7379x over previous
//
#include <hip/hip_runtime.h>
#include <hip/hip_bf16.h>
#include <math.h>

#define B_ 2
#define T_ 2048
#define D_ 512
#define H_ 16
#define DH 32
#define L_ 64
#define C_ 32
#define NC 1024    // total chunks
#define VTP 72     // LDS row stride (ushorts) for chunk kernels
#define CSZ 1056   // floats per chunk state tile (33 rows x 32)

typedef __attribute__((ext_vector_type(8))) short bf16x8;
typedef __attribute__((ext_vector_type(4))) float f32x4;
typedef __attribute__((ext_vector_type(4))) unsigned short u16x4;

#define AS1 __attribute__((address_space(1)))
#define AS3 __attribute__((address_space(3)))

__device__ __forceinline__ float bf2f(unsigned short u) {
    union { float f; unsigned int i; } v; v.i = ((unsigned int)u) << 16; return v.f;
}
__device__ __forceinline__ unsigned short f2bf(float f) {
    union { float f; unsigned int u; } v; v.f = f;
    unsigned int u = v.u;
    unsigned int r = u + 0x7FFFu + ((u >> 16) & 1u);
    return (unsigned short)(r >> 16);
}
// compiler-visible RNE conversion (lets hipcc emit v_cvt_pk_bf16_f32 for pairs)
__device__ __forceinline__ unsigned short f2bf_rne(float f) {
    __hip_bfloat16 h = __float2bfloat16(f);
    union { __hip_bfloat16 h; unsigned short u; } v; v.h = h; return v.u;
}
__device__ __forceinline__ bf16x8 phi_frag(bf16x8 in) {
    bf16x8 r;
    #pragma unroll
    for (int i = 0; i < 8; ++i) {
        float f = bf2f((unsigned short)in[i]);
        f = f > 0.f ? f + 1.f : __expf(f);
        r[i] = (short)f2bf(f);
    }
    return r;
}
__device__ __forceinline__ void gload_lds16(const unsigned short* g, unsigned short* l) {
    __builtin_amdgcn_global_load_lds((const AS1 unsigned int*)g, (AS3 unsigned int*)l, 16, 0, 0);
}

// C[m][n] = sum_k A[m][k]*W[n][k]; BMx128 tile, 4 waves (2x2), 16x16x32 bf16 MFMA.
// W is always fp32, converted during reg-staging (T14: load early, cvt+ds_write late).
// A is fp32 (reg-staged convert) when AF32, else bf16 via async global_load_lds.
template<int BM, bool AF32, bool OUT_BF16>
__global__ __launch_bounds__(256) void gemm_nt(const void* __restrict__ Aptr,
                                               const float* __restrict__ Wf,
                                               void* __restrict__ Cout,
                                               int N, int K)
{
    constexpr int MF = BM / 32;        // m-fragments per wave
    constexpr int AF4 = BM / 32;       // float4 loads per lane for fp32 A staging
    __shared__ unsigned short As[2][BM][32];
    __shared__ unsigned short Bs[2][128][32];
    const int tid = threadIdx.x;
    const int lane = tid & 63;
    const int wave = tid >> 6;
    const int wr = wave >> 1;
    const int wc = wave & 1;
    const size_t bm = (size_t)blockIdx.x * BM;
    const size_t bn = (size_t)blockIdx.y * 128;

    const int r8 = lane >> 3;          // 0..7 (f32 staging row-in-group)
    const int c4 = (lane & 7) * 4;     // f32 staging col (floats)
    const int lrow = lane >> 2;        // bf16 gload row
    const int lcol = (lane & 3) * 8;   // bf16 gload col

    const float* agf = nullptr;
    const unsigned short* agb = nullptr;
    if constexpr (AF32) agf = (const float*)Aptr + (bm + wave * (BM / 4) + r8) * (size_t)K + c4;
    else                agb = (const unsigned short*)Aptr + (bm + wave * (BM / 4) + lrow) * (size_t)K + lcol;
    const float* wgf = Wf + (bn + wave * 32 + r8) * (size_t)K + c4;

    f32x4 aL[AF4];
    f32x4 wL[4];

    auto load_stage = [&](int buf, int k0) {
        if constexpr (AF32) {
            #pragma unroll
            for (int i = 0; i < AF4; ++i)
                aL[i] = *(const f32x4*)(agf + k0 + (size_t)(i * 8) * K);
        } else {
            gload_lds16(agb + k0, &As[buf][wave * (BM / 4)][0]);
            if constexpr (BM / 4 == 32)
                gload_lds16(agb + (size_t)16 * K + k0, &As[buf][wave * (BM / 4) + 16][0]);
        }
        #pragma unroll
        for (int i = 0; i < 4; ++i)
            wL[i] = *(const f32x4*)(wgf + k0 + (size_t)(i * 8) * K);
    };
    auto write_stage = [&](int buf) {
        if constexpr (AF32) {
            #pragma unroll
            for (int i = 0; i < AF4; ++i) {
                u16x4 o;
                o.x = f2bf_rne(aL[i][0]); o.y = f2bf_rne(aL[i][1]);
                o.z = f2bf_rne(aL[i][2]); o.w = f2bf_rne(aL[i][3]);
                *(u16x4*)&As[buf][wave * (BM / 4) + r8 + i * 8][c4] = o;
            }
        }
        #pragma unroll
        for (int i = 0; i < 4; ++i) {
            u16x4 o;
            o.x = f2bf_rne(wL[i][0]); o.y = f2bf_rne(wL[i][1]);
            o.z = f2bf_rne(wL[i][2]); o.w = f2bf_rne(wL[i][3]);
            *(u16x4*)&Bs[buf][wave * 32 + r8 + i * 8][c4] = o;
        }
    };

    f32x4 acc[MF][4];
    #pragma unroll
    for (int m = 0; m < MF; ++m)
        #pragma unroll
        for (int n = 0; n < 4; ++n)
            acc[m][n] = (f32x4){0.f, 0.f, 0.f, 0.f};

    const int rr = lane & 15;
    const int kb = (lane >> 4) * 8;

    load_stage(0, 0);
    write_stage(0);
    __syncthreads();
    int cur = 0;
    for (int k0 = 0; k0 < K; k0 += 32) {
        const bool more = k0 + 32 < K;
        if (more) load_stage(cur ^ 1, k0 + 32);   // issue loads early (latency under MFMA)
        bf16x8 af[MF], bfr[4];
        #pragma unroll
        for (int m = 0; m < MF; ++m)
            af[m] = *(const bf16x8*)&As[cur][wr * (BM / 2) + m * 16 + rr][kb];
        #pragma unroll
        for (int n = 0; n < 4; ++n)
            bfr[n] = *(const bf16x8*)&Bs[cur][wc * 64 + n * 16 + rr][kb];
        #pragma unroll
        for (int m = 0; m < MF; ++m)
            #pragma unroll
            for (int n = 0; n < 4; ++n)
                acc[m][n] = __builtin_amdgcn_mfma_f32_16x16x32_bf16(af[m], bfr[n], acc[m][n], 0, 0, 0);
        if (more) write_stage(cur ^ 1);           // convert + ds_write late
        __syncthreads();
        cur ^= 1;
    }

    const int cr = (lane >> 4) * 4;
    const int cc = lane & 15;
    #pragma unroll
    for (int m = 0; m < MF; ++m)
        #pragma unroll
        for (int n = 0; n < 4; ++n)
            #pragma unroll
            for (int j = 0; j < 4; ++j) {
                size_t row = bm + wr * (BM / 2) + m * 16 + cr + j;
                size_t col = bn + wc * 64 + n * 16 + cc;
                float v = acc[m][n][j];
                if (OUT_BF16) ((unsigned short*)Cout)[row * N + col] = f2bf(v);
                else          ((float*)Cout)[row * N + col] = v;
            }
}

// Per-chunk ST[e][d] = sum_t v_ext[t][e]*phi(k)[t][d], e=0..32 (row 32 = ksum).
__global__ __launch_bounds__(256) void chunk_sum(const unsigned short* __restrict__ qkv,
                                                 float* __restrict__ cSf)
{
    __shared__ unsigned short Kt[4][DH][VTP];
    __shared__ unsigned short Vt[4][48][VTP];
    const int tid = threadIdx.x;
    const int lane = tid & 63;
    const int wave = tid >> 6;
    const int chunk = blockIdx.x * 4 + wave;
    const int c = chunk & 31;
    const int h = (chunk >> 5) & 15;
    const int b = chunk >> 9;
    const size_t rowbase = ((size_t)(b * T_ + c * L_)) * (3 * D_) + h * DH;
    const int half = lane & 1;

    #pragma unroll
    for (int it = 0; it < 2; ++it) {
        int t = (lane >> 1) + it * 32;
        const unsigned short* kp = qkv + rowbase + (size_t)t * (3 * D_) + D_ + half * 16;
        const unsigned short* vp = qkv + rowbase + (size_t)t * (3 * D_) + 2 * D_ + half * 16;
        bf16x8 k0 = phi_frag(*(const bf16x8*)kp);
        bf16x8 k1 = phi_frag(*(const bf16x8*)(kp + 8));
        bf16x8 v0 = *(const bf16x8*)vp;
        bf16x8 v1 = *(const bf16x8*)(vp + 8);
        #pragma unroll
        for (int i = 0; i < 8; ++i) {
            Kt[wave][half * 16 + i][t]     = (unsigned short)k0[i];
            Kt[wave][half * 16 + 8 + i][t] = (unsigned short)k1[i];
            Vt[wave][half * 16 + i][t]     = (unsigned short)v0[i];
            Vt[wave][half * 16 + 8 + i][t] = (unsigned short)v1[i];
        }
    }
    Vt[wave][32][lane] = 0x3F80;   // ones row

    const int fr = lane & 15;
    const int fg = lane >> 4;
    f32x4 acc[3][2];
    #pragma unroll
    for (int m = 0; m < 3; ++m)
        #pragma unroll
        for (int n = 0; n < 2; ++n)
            acc[m][n] = (f32x4){0.f, 0.f, 0.f, 0.f};

    #pragma unroll
    for (int ks = 0; ks < 2; ++ks) {
        int toff = fg * 8 + ks * 32;
        bf16x8 av[3], bk[2];
        #pragma unroll
        for (int m = 0; m < 3; ++m) av[m] = *(const bf16x8*)&Vt[wave][m * 16 + fr][toff];
        #pragma unroll
        for (int n = 0; n < 2; ++n) bk[n] = *(const bf16x8*)&Kt[wave][n * 16 + fr][toff];
        #pragma unroll
        for (int m = 0; m < 3; ++m)
            #pragma unroll
            for (int n = 0; n < 2; ++n)
                acc[m][n] = __builtin_amdgcn_mfma_f32_16x16x32_bf16(av[m], bk[n], acc[m][n], 0, 0, 0);
    }

    float* outp = cSf + (size_t)chunk * CSZ;
    #pragma unroll
    for (int m = 0; m < 2; ++m)
        #pragma unroll
        for (int n = 0; n < 2; ++n)
            #pragma unroll
            for (int r = 0; r < 4; ++r)
                outp[(m * 16 + fg * 4 + r) * 32 + n * 16 + fr] = acc[m][n][r];
    if (fg == 0) {
        #pragma unroll
        for (int n = 0; n < 2; ++n)
            outp[32 * 32 + n * 16 + fr] = acc[2][n][0];
    }
}

// Exclusive prefix over chunks; emit bf16 state cSt[chunk][e*32+d].
// All 32 loads issued up front (independent), then register prefix + stores.
__global__ __launch_bounds__(256) void chunk_scan(const float* __restrict__ cSf,
                                                  unsigned short* __restrict__ cSt)
{
    int idx = blockIdx.x * 256 + threadIdx.x;     // 32*1056 = 33792 exactly
    int bh = idx / CSZ;
    int r  = idx % CSZ;
    const float* src = cSf + (size_t)bh * C_ * CSZ + r;
    unsigned short* dst = cSt + (size_t)bh * C_ * CSZ + r;
    float v[C_];
    #pragma unroll
    for (int c = 0; c < C_; ++c) v[c] = src[(size_t)c * CSZ];
    float acc = 0.f;
    #pragma unroll
    for (int c = 0; c < C_; ++c) {
        dst[(size_t)c * CSZ] = f2bf(acc);
        acc += v[c];
    }
}

// Per-chunk output via MFMA. 2 waves per chunk (row halves), 2 chunks per block.
__global__ __launch_bounds__(256) void chunk_out(const unsigned short* __restrict__ qkv,
                                                 const unsigned short* __restrict__ cSt,
                                                 unsigned short* __restrict__ attn)
{
    __shared__ unsigned short Vt[2][48][VTP];
    __shared__ unsigned short Am[4][32][VTP];
    const int tid = threadIdx.x;
    const int lane = tid & 63;
    const int wave = tid >> 6;
    const int ci = wave >> 1;
    const int wh = wave & 1;
    const int chunk = blockIdx.x * 2 + ci;
    const int c = chunk & 31;
    const int h = (chunk >> 5) & 15;
    const int b = chunk >> 9;
    const size_t rowbase = ((size_t)(b * T_ + c * L_)) * (3 * D_) + h * DH;
    const int fr = lane & 15;
    const int fg = lane >> 4;

    {
        int t = wh * 32 + (lane >> 1);
        int half = lane & 1;
        const unsigned short* vp = qkv + rowbase + (size_t)t * (3 * D_) + 2 * D_ + half * 16;
        bf16x8 v0 = *(const bf16x8*)vp;
        bf16x8 v1 = *(const bf16x8*)(vp + 8);
        #pragma unroll
        for (int i = 0; i < 8; ++i) {
            Vt[ci][half * 16 + i][t]     = (unsigned short)v0[i];
            Vt[ci][half * 16 + 8 + i][t] = (unsigned short)v1[i];
        }
        if (half == 0) Vt[ci][32][t] = 0x3F80;
    }

    bf16x8 aq[2];
    #pragma unroll
    for (int mm = 0; mm < 2; ++mm) {
        int m = wh * 2 + mm;
        const unsigned short* qp = qkv + rowbase + (size_t)(m * 16 + fr) * (3 * D_) + fg * 8;
        aq[mm] = phi_frag(*(const bf16x8*)qp);
    }
    bf16x8 bk[4];
    const int nmax = wh * 2 + 1;
    #pragma unroll
    for (int n = 0; n < 4; ++n) {
        if (n <= nmax) {
            const unsigned short* kp = qkv + rowbase + (size_t)(n * 16 + fr) * (3 * D_) + D_ + fg * 8;
            bk[n] = phi_frag(*(const bf16x8*)kp);
        }
    }
    bf16x8 bkv[3];
    #pragma unroll
    for (int n = 0; n < 3; ++n)
        bkv[n] = *(const bf16x8*)&cSt[(size_t)chunk * CSZ + (size_t)(n * 16 + fr) * 32 + fg * 8];

    f32x4 zero = (f32x4){0.f, 0.f, 0.f, 0.f};
    f32x4 acc[2][3];
    #pragma unroll
    for (int mm = 0; mm < 2; ++mm)
        #pragma unroll
        for (int n = 0; n < 3; ++n)
            acc[mm][n] = __builtin_amdgcn_mfma_f32_16x16x32_bf16(aq[mm], bkv[n], zero, 0, 0, 0);

    #pragma unroll
    for (int mm = 0; mm < 2; ++mm) {
        int m = wh * 2 + mm;
        #pragma unroll
        for (int n = 0; n < 4; ++n) {
            if (n <= m) {
                f32x4 s = __builtin_amdgcn_mfma_f32_16x16x32_bf16(aq[mm], bk[n], zero, 0, 0, 0);
                #pragma unroll
                for (int r = 0; r < 4; ++r) {
                    unsigned short v = f2bf(s[r]);
                    if (n == m && fr > fg * 4 + r) v = 0;
                    Am[wave][mm * 16 + fg * 4 + r][n * 16 + fr] = v;
                }
            }
        }
    }
    {
        int zc = wh ? 48 : 16;
        *(uint2*)&Am[wave][fr][zc + fg * 4] = (uint2){0u, 0u};
    }
    __syncthreads();

    #pragma unroll
    for (int ks = 0; ks < 2; ++ks) {
        if (ks <= wh) {
            bf16x8 bv[3];
            #pragma unroll
            for (int n = 0; n < 3; ++n)
                bv[n] = *(const bf16x8*)&Vt[ci][n * 16 + fr][fg * 8 + ks * 32];
            #pragma unroll
            for (int mm = 0; mm < 2; ++mm) {
                bf16x8 aa = *(const bf16x8*)&Am[wave][mm * 16 + fr][fg * 8 + ks * 32];
                #pragma unroll
                for (int n = 0; n < 3; ++n)
                    acc[mm][n] = __builtin_amdgcn_mfma_f32_16x16x32_bf16(aa, bv[n], acc[mm][n], 0, 0, 0);
            }
        }
    }

    #pragma unroll
    for (int mm = 0; mm < 2; ++mm) {
        float dn[4];
        #pragma unroll
        for (int r = 0; r < 4; ++r)
            dn[r] = __shfl(acc[mm][2][r], lane & 48);
        #pragma unroll
        for (int r = 0; r < 4; ++r) {
            float inv = 1.0f / fmaxf(dn[r], 1e-6f);
            #pragma unroll
            for (int n = 0; n < 2; ++n)
                Am[wave][mm * 16 + fg * 4 + r][n * 16 + fr] = f2bf(acc[mm][n][r] * inv);
        }
    }
    {
        int lrow = lane >> 1;
        int half = lane & 1;
        uint4 q0 = *(const uint4*)&Am[wave][lrow][half * 16];
        uint4 q1 = *(const uint4*)&Am[wave][lrow][half * 16 + 8];
        size_t grow = (size_t)(b * T_ + c * L_ + wh * 32 + lrow);
        unsigned short* dst = attn + grow * D_ + h * DH + half * 16;
        *(uint4*)dst = q0;
        *(uint4*)(dst + 8) = q1;
    }
}

extern "C" void kernel_launch(void* const* d_in, const int* in_sizes, int n_in,
                              void* d_out, int out_size, void* d_ws, size_t ws_size,
                              hipStream_t stream) {
    const float* x     = (const float*)d_in[0];
    const float* w_qkv = (const float*)d_in[1];
    const float* w_out = (const float*)d_in[2];
    float* out = (float*)d_out;

    char* ws = (char*)d_ws;
    unsigned short* qkvb  = (unsigned short*)ws;                 // 12,582,912 B
    unsigned short* attnb = (unsigned short*)(ws + 12582912);    //  4,194,304 B
    float* cSf            = (float*)(ws + 16777216);             //  4,325,376 B  [1024][1056] f32
    unsigned short* cSt   = (unsigned short*)(ws + 21102592);    //  2,162,688 B  [1024][1056] bf16
    // total 23,265,280 B

    // 1) QKV projection: fp32 x / fp32 w_qkv -> bf16 qkv (convert fused into staging)
    //    BM=64 -> 768 blocks = 3.0 blocks/CU exact (was 384 = 1.5/CU, half-chip tail)
    gemm_nt<64, true, true><<<dim3(4096 / 64, 1536 / 128), 256, 0, stream>>>(
        x, w_qkv, qkvb, 1536, 512);

    // 2) per-chunk local sums
    chunk_sum<<<NC / 4, 256, 0, stream>>>(qkvb, cSf);

    // 3) exclusive prefix over chunks (dedicated kernel: upfront loads, full-width grid)
    chunk_scan<<<132, 256, 0, stream>>>(cSf, cSt);

    // 4) per-chunk outputs -> bf16 attn
    chunk_out<<<NC / 2, 256, 0, stream>>>(qkvb, cSt, attnb);

    // 5) output projection: bf16 attn (gload_lds) / fp32 w_out -> fp32 out
    gemm_nt<64, false, false><<<dim3(4096 / 64, 512 / 128), 256, 0, stream>>>(
        attnb, w_out, out, 512, 512);
}